// Round 1
// baseline (2975.922 us; speedup 1.0000x reference)
//
#include <hip/hip_runtime.h>
#include <hip/hip_bf16.h>
#include <math.h>

// Problem constants (from reference): B graphs, N points, C=64 channels.
constexpr int B = 32;
constexpr int N = 2048;

// ---------------------------------------------------------------------------
// dtype sniffer: decides whether float inputs are bf16 (expected) or fp32.
// For a bf16 array viewed as u32 words, byte1 of each word is (sign|exp>>1) of
// a N(0,1) bf16 value -> in [0x3a,0x41] (masked) ~99% of the time. For fp32,
// that byte is uniform mantissa bits (~6% hit rate). flag=1 => bf16.
// ---------------------------------------------------------------------------
__global__ void detect_kernel(const unsigned int* __restrict__ raw, int* __restrict__ flag) {
    __shared__ int cnt;
    if (threadIdx.x == 0) cnt = 0;
    __syncthreads();
    int c = 0;
    for (int i = threadIdx.x; i < 4096; i += 256) {
        unsigned h = (raw[i] >> 8) & 0x7f;
        if (h >= 0x3a && h <= 0x41) c++;
    }
    atomicAdd(&cnt, c);
    __syncthreads();
    if (threadIdx.x == 0) *flag = (cnt > (4096 * 55) / 100) ? 1 : 0;
}

__global__ void b2f_kernel(const void* __restrict__ in, float* __restrict__ out, int n,
                           const int* __restrict__ flag) {
    int i = blockIdx.x * 256 + threadIdx.x;
    if (i >= n) return;
    if (*flag) out[i] = __bfloat162float(((const __hip_bfloat16*)in)[i]);
    else       out[i] = ((const float*)in)[i];
}

struct B2FMulti {
    const void* src[14];
    float* dst[14];
    int n[14];
};

__global__ void b2f_multi_kernel(B2FMulti p, const int* __restrict__ flag) {
    int a = blockIdx.y;
    int i = blockIdx.x * 256 + threadIdx.x;
    if (i >= p.n[a]) return;
    if (*flag) p.dst[a][i] = __bfloat162float(((const __hip_bfloat16*)p.src[a])[i]);
    else       p.dst[a][i] = ((const float*)p.src[a])[i];
}

// ---------------------------------------------------------------------------
// KNN: for each query point, k smallest squared distances (lexicographic
// (d2, idx) order == stable top_k of -d2). Includes self (d2 = 0).
// Block: 256 query points; candidates staged in LDS tiles of 256.
// ---------------------------------------------------------------------------
template <int K>
__global__ void __launch_bounds__(256) knn_kernel(const float* __restrict__ pos,
                                                  int* __restrict__ idx_out, int n) {
    #pragma clang fp contract(off)
    const int b = blockIdx.y;
    const int i = blockIdx.x * 256 + threadIdx.x;
    const float* pb = pos + (size_t)b * n * 3;
    const float xi = pb[i * 3 + 0], yi = pb[i * 3 + 1], zi = pb[i * 3 + 2];

    float bd[K];
    int   bi_[K];
    #pragma unroll
    for (int q = 0; q < K; ++q) { bd[q] = __builtin_inff(); bi_[q] = 0x7fffffff; }

    __shared__ float tx[256], ty[256], tz[256];
    for (int t0 = 0; t0 < n; t0 += 256) {
        __syncthreads();
        {
            int j = t0 + threadIdx.x;
            tx[threadIdx.x] = pb[j * 3 + 0];
            ty[threadIdx.x] = pb[j * 3 + 1];
            tz[threadIdx.x] = pb[j * 3 + 2];
        }
        __syncthreads();
        for (int jj = 0; jj < 256; ++jj) {
            float dx = xi - tx[jj], dy = yi - ty[jj], dz = zi - tz[jj];
            float d2 = (dx * dx + dy * dy) + dz * dz;   // contract off: matches numpy
            int jg = t0 + jj;
            if (d2 < bd[K - 1] || (d2 == bd[K - 1] && jg < bi_[K - 1])) {
                bd[K - 1] = d2; bi_[K - 1] = jg;
                #pragma unroll
                for (int q = K - 1; q > 0; --q) {
                    bool sw = (bd[q] < bd[q - 1]) || (bd[q] == bd[q - 1] && bi_[q] < bi_[q - 1]);
                    if (sw) {
                        float td = bd[q]; bd[q] = bd[q - 1]; bd[q - 1] = td;
                        int   ti = bi_[q]; bi_[q] = bi_[q - 1]; bi_[q - 1] = ti;
                    }
                }
            }
        }
    }
    int* op = idx_out + ((size_t)b * n + i) * K;
    #pragma unroll
    for (int q = 0; q < K; ++q) op[q] = bi_[q];
}

// ---------------------------------------------------------------------------
// FPS: one block (256 threads) per graph. d[] lives in registers (P per
// thread, contiguous ownership), positions staged in LDS. Argmax reduce:
// per-thread scan -> wave shfl butterfly -> cross-wave via double-buffered
// LDS slots (1 barrier per iteration). Tie-break: first (lowest) index, same
// as jnp.argmax. Distances with contract(off) to bit-match numpy fp32.
// ---------------------------------------------------------------------------
template <int NPTS>
__global__ void __launch_bounds__(256) fps_kernel(const float* __restrict__ pos,
                                                  int* __restrict__ sel, int m) {
    #pragma clang fp contract(off)
    constexpr int P = NPTS / 256;
    const int b = blockIdx.x, t = threadIdx.x;
    const float* pb = pos + (size_t)b * NPTS * 3;

    __shared__ float px[NPTS], py[NPTS], pz[NPTS];
    __shared__ float rv[8];
    __shared__ int   ri[8];

    for (int i = t; i < NPTS; i += 256) {
        px[i] = pb[i * 3 + 0]; py[i] = pb[i * 3 + 1]; pz[i] = pb[i * 3 + 2];
    }
    __syncthreads();

    const float sx = px[0], sy = py[0], sz = pz[0];
    float d[P], ox[P], oy[P], oz[P];
    #pragma unroll
    for (int p = 0; p < P; ++p) {
        int ii = t * P + p;
        ox[p] = px[ii]; oy[p] = py[ii]; oz[p] = pz[ii];
        float dx = ox[p] - sx, dy = oy[p] - sy, dz = oz[p] - sz;
        d[p] = (dx * dx + dy * dy) + dz * dz;
    }
    if (t == 0) sel[(size_t)b * m + 0] = 0;

    for (int it = 1; it < m; ++it) {
        // local argmax (ascending index scan + strict > keeps lowest index)
        float bv = d[0];
        int bix = t * P;
        #pragma unroll
        for (int p = 1; p < P; ++p) {
            if (d[p] > bv) { bv = d[p]; bix = t * P + p; }
        }
        // wave butterfly: max value, tie -> lower index
        #pragma unroll
        for (int o = 1; o < 64; o <<= 1) {
            float v2 = __shfl_xor(bv, o, 64);
            int   i2 = __shfl_xor(bix, o, 64);
            if (v2 > bv || (v2 == bv && i2 < bix)) { bv = v2; bix = i2; }
        }
        int slot = (it & 1) * 4 + (t >> 6);
        if ((t & 63) == 0) { rv[slot] = bv; ri[slot] = bix; }
        __syncthreads();
        int base = (it & 1) * 4;
        bv = rv[base]; bix = ri[base];
        #pragma unroll
        for (int q = 1; q < 4; ++q) {
            float v2 = rv[base + q]; int i2 = ri[base + q];
            if (v2 > bv || (v2 == bv && i2 < bix)) { bv = v2; bix = i2; }
        }
        if (t == 0) sel[(size_t)b * m + it] = bix;
        float nx = px[bix], ny = py[bix], nz = pz[bix];
        #pragma unroll
        for (int p = 0; p < P; ++p) {
            float dx = ox[p] - nx, dy = oy[p] - ny, dz = oz[p] - nz;
            float dd = (dx * dx + dy * dy) + dz * dz;
            d[p] = fminf(d[p], dd);
        }
    }
}

// ---------------------------------------------------------------------------
// Gather p/h by fps selection. 64 consecutive threads = one output point.
// ---------------------------------------------------------------------------
__global__ void gather_kernel(const float* __restrict__ p_in, const float* __restrict__ h_in,
                              const int* __restrict__ sel, float* __restrict__ p_out,
                              float* __restrict__ h_out, int n_in, int m) {
    const int b = blockIdx.y;
    const int tid = blockIdx.x * 256 + threadIdx.x;
    const int t = tid >> 6, c = tid & 63;
    if (t >= m) return;
    const int s = sel[(size_t)b * m + t];
    h_out[((size_t)b * m + t) * 64 + c] = h_in[((size_t)b * n_in + s) * 64 + c];
    if (c < 3) p_out[((size_t)b * m + t) * 3 + c] = p_in[((size_t)b * n_in + s) * 3 + c];
}

// ---------------------------------------------------------------------------
// PointNet layer, CHIN=3 (layer 1: h = pos, m = [pos_i, pos_j, rel], DIN=9).
// Lane-per-point: each lane owns one point; 64 fp32 accumulators for the
// hidden layer (weights fetched as lane-uniform scalar loads), LDS transpose
// of `a` so the second 64x64 GEMM can stream e dynamically.
// ---------------------------------------------------------------------------
__global__ void __launch_bounds__(64) pointnet3_kernel(
        const float* __restrict__ pos, const int* __restrict__ idx,
        const float* __restrict__ W1, const float* __restrict__ b1,
        const float* __restrict__ W2, const float* __restrict__ b2,
        float* __restrict__ out, int n, int k) {
    const int b = blockIdx.y, lane = threadIdx.x;
    const int i = blockIdx.x * 64 + lane;
    const float* pb = pos + (size_t)b * n * 3;
    const float xi = pb[i * 3 + 0], yi = pb[i * 3 + 1], zi = pb[i * 3 + 2];

    __shared__ float a_lds[64 * 64];

    float acc[64];
    #pragma unroll
    for (int c = 0; c < 64; ++c) acc[c] = -__builtin_inff();

    const int* idxp = idx + ((size_t)b * n + i) * k;
    for (int kk = 0; kk < k; ++kk) {
        const int j = idxp[kk];
        const float xj = pb[j * 3 + 0], yj = pb[j * 3 + 1], zj = pb[j * 3 + 2];
        const float mv[9] = {xi, yi, zi, xj, yj, zj, xj - xi, yj - yi, zj - zi};
        float a[64];
        #pragma unroll
        for (int e = 0; e < 64; ++e) a[e] = b1[e];
        #pragma unroll
        for (int d = 0; d < 9; ++d) {
            #pragma unroll
            for (int e = 0; e < 64; ++e) a[e] = fmaf(mv[d], W1[d * 64 + e], a[e]);
        }
        __syncthreads();   // previous iteration's a_lds reads are done
        #pragma unroll
        for (int e = 0; e < 64; ++e) a_lds[e * 64 + lane] = fmaxf(a[e], 0.f);
        __syncthreads();
        float o[64];
        #pragma unroll
        for (int c = 0; c < 64; ++c) o[c] = b2[c];
        for (int e = 0; e < 64; ++e) {
            float av = a_lds[e * 64 + lane];
            #pragma unroll
            for (int c = 0; c < 64; ++c) o[c] = fmaf(av, W2[e * 64 + c], o[c]);
        }
        #pragma unroll
        for (int c = 0; c < 64; ++c) acc[c] = fmaxf(acc[c], o[c]);
    }
    float* op = out + ((size_t)b * n + i) * 64;
    #pragma unroll
    for (int c = 0; c < 64; ++c) op[c] = fmaxf(acc[c], 0.f);
}

// ---------------------------------------------------------------------------
// PointNet layer, CHIN=64 (layers 2/3: DIN = 131 = [h_i(64), h_j(64), rel(3)]).
// h_i/h_j streamed as float4 gathers inside the dynamic d-loop.
// ---------------------------------------------------------------------------
__global__ void __launch_bounds__(64) pointnet64_kernel(
        const float* __restrict__ h_in, const float* __restrict__ pos,
        const int* __restrict__ idx,
        const float* __restrict__ W1, const float* __restrict__ b1,
        const float* __restrict__ W2, const float* __restrict__ b2,
        float* __restrict__ out, int n, int k) {
    const int b = blockIdx.y, lane = threadIdx.x;
    const int i = blockIdx.x * 64 + lane;
    const float* pb = pos + (size_t)b * n * 3;
    const float* hb = h_in + (size_t)b * n * 64;
    const float xi = pb[i * 3 + 0], yi = pb[i * 3 + 1], zi = pb[i * 3 + 2];

    __shared__ float a_lds[64 * 64];

    float acc[64];
    #pragma unroll
    for (int c = 0; c < 64; ++c) acc[c] = -__builtin_inff();

    const int* idxp = idx + ((size_t)b * n + i) * k;
    const float* hi = hb + (size_t)i * 64;
    for (int kk = 0; kk < k; ++kk) {
        const int j = idxp[kk];
        const float xj = pb[j * 3 + 0], yj = pb[j * 3 + 1], zj = pb[j * 3 + 2];
        const float* hj = hb + (size_t)j * 64;

        float a[64];
        #pragma unroll
        for (int e = 0; e < 64; ++e) a[e] = b1[e];

        // h_i part: W1 rows 0..63
        for (int d4 = 0; d4 < 16; ++d4) {
            float4 v = *(const float4*)(hi + d4 * 4);
            const float mu[4] = {v.x, v.y, v.z, v.w};
            const float* wr = W1 + (size_t)(d4 * 4) * 64;
            #pragma unroll
            for (int u = 0; u < 4; ++u) {
                #pragma unroll
                for (int e = 0; e < 64; ++e) a[e] = fmaf(mu[u], wr[u * 64 + e], a[e]);
            }
        }
        // h_j part: W1 rows 64..127
        for (int d4 = 0; d4 < 16; ++d4) {
            float4 v = *(const float4*)(hj + d4 * 4);
            const float mu[4] = {v.x, v.y, v.z, v.w};
            const float* wr = W1 + (size_t)(64 + d4 * 4) * 64;
            #pragma unroll
            for (int u = 0; u < 4; ++u) {
                #pragma unroll
                for (int e = 0; e < 64; ++e) a[e] = fmaf(mu[u], wr[u * 64 + e], a[e]);
            }
        }
        // rel part: W1 rows 128..130
        {
            const float mr[3] = {xj - xi, yj - yi, zj - zi};
            #pragma unroll
            for (int d = 0; d < 3; ++d) {
                #pragma unroll
                for (int e = 0; e < 64; ++e) a[e] = fmaf(mr[d], W1[(128 + d) * 64 + e], a[e]);
            }
        }
        __syncthreads();
        #pragma unroll
        for (int e = 0; e < 64; ++e) a_lds[e * 64 + lane] = fmaxf(a[e], 0.f);
        __syncthreads();
        float o[64];
        #pragma unroll
        for (int c = 0; c < 64; ++c) o[c] = b2[c];
        for (int e = 0; e < 64; ++e) {
            float av = a_lds[e * 64 + lane];
            #pragma unroll
            for (int c = 0; c < 64; ++c) o[c] = fmaf(av, W2[e * 64 + c], o[c]);
        }
        #pragma unroll
        for (int c = 0; c < 64; ++c) acc[c] = fmaxf(acc[c], o[c]);
    }
    float* op = out + ((size_t)b * n + i) * 64;
    #pragma unroll
    for (int c = 0; c < 64; ++c) op[c] = fmaxf(acc[c], 0.f);
}

// ---------------------------------------------------------------------------
// Head: global max over points then [64]x[64,6] linear. One block per graph.
// ---------------------------------------------------------------------------
__global__ void __launch_bounds__(64) head_kernel(const float* __restrict__ h,
                                                  const float* __restrict__ Wr,
                                                  const float* __restrict__ br,
                                                  void* __restrict__ out, int n,
                                                  const int* __restrict__ flag) {
    const int b = blockIdx.x, lane = threadIdx.x;
    const float* hb = h + (size_t)b * n * 64;
    float g = -__builtin_inff();
    for (int i = 0; i < n; ++i) g = fmaxf(g, hb[(size_t)i * 64 + lane]);
    __shared__ float gl[64];
    gl[lane] = g;
    __syncthreads();
    if (lane < 6) {
        float o = br[lane];
        #pragma unroll
        for (int c = 0; c < 64; ++c) o = fmaf(gl[c], Wr[c * 6 + lane], o);
        if (*flag) ((__hip_bfloat16*)out)[b * 6 + lane] = __float2bfloat16(o);
        else       ((float*)out)[b * 6 + lane] = o;
    }
}

// ---------------------------------------------------------------------------
extern "C" void kernel_launch(void* const* d_in, const int* in_sizes, int n_in,
                              void* d_out, int out_size, void* d_ws, size_t ws_size,
                              hipStream_t stream) {
    (void)in_sizes; (void)n_in; (void)out_size; (void)ws_size;

    char* w = (char*)d_ws;
    auto alloc = [&](size_t nbytes) -> void* {
        void* p = (void*)w;
        w += (nbytes + 255) & ~(size_t)255;
        return p;
    };

    int*   flag = (int*)alloc(4);
    float* posf = (float*)alloc((size_t)B * N * 3 * 4);
    float* W1a = (float*)alloc(9 * 64 * 4);    float* b1a = (float*)alloc(64 * 4);
    float* W1b = (float*)alloc(64 * 64 * 4);   float* b1b = (float*)alloc(64 * 4);
    float* W2a = (float*)alloc(131 * 64 * 4);  float* b2a = (float*)alloc(64 * 4);
    float* W2b = (float*)alloc(64 * 64 * 4);   float* b2b = (float*)alloc(64 * 4);
    float* W3a = (float*)alloc(131 * 64 * 4);  float* b3a = (float*)alloc(64 * 4);
    float* W3b = (float*)alloc(64 * 64 * 4);   float* b3b = (float*)alloc(64 * 4);
    float* Wr  = (float*)alloc(64 * 6 * 4);    float* br  = (float*)alloc(6 * 4);

    float* h1    = (float*)alloc((size_t)B * N * 64 * 4);       // 16 MB (re-sliced below)
    int*   idx1  = (int*)alloc((size_t)B * N * 6 * 4);
    int*   sel1  = (int*)alloc((size_t)B * 1024 * 4);
    float* p2    = (float*)alloc((size_t)B * 1024 * 3 * 4);
    float* h2in  = (float*)alloc((size_t)B * 1024 * 64 * 4);
    int*   idx2  = (int*)alloc((size_t)B * 1024 * 4 * 4);
    int*   sel2  = (int*)alloc((size_t)B * 512 * 4);
    float* p3    = (float*)alloc((size_t)B * 512 * 3 * 4);
    int*   idx3  = (int*)alloc((size_t)B * 512 * 3 * 4);
    // Alias later stages into h1's 16 MB once h1 is consumed (after gather 1):
    float* h2out = h1;                                           // 8 MB
    float* h3in  = h1 + (size_t)B * 1024 * 64;                   // 4 MB
    float* h3out = h1 + (size_t)B * 1024 * 64 + (size_t)B * 512 * 64; // 4 MB

    // --- dtype detect + convert everything to fp32 in ws ---
    detect_kernel<<<dim3(1), 256, 0, stream>>>((const unsigned int*)d_in[1], flag);
    b2f_kernel<<<dim3((B * N * 3 + 255) / 256), 256, 0, stream>>>(d_in[1], posf, B * N * 3, flag);
    B2FMulti mp;
    {
        const int   wi[14] = {3, 4, 5, 6, 7, 8, 9, 10, 11, 12, 13, 14, 15, 16};
        float*      wd[14] = {W1a, b1a, W1b, b1b, W2a, b2a, W2b, b2b, W3a, b3a, W3b, b3b, Wr, br};
        const int   wn[14] = {576, 64, 4096, 64, 8384, 64, 4096, 64, 8384, 64, 4096, 64, 384, 6};
        for (int q = 0; q < 14; ++q) { mp.src[q] = d_in[wi[q]]; mp.dst[q] = wd[q]; mp.n[q] = wn[q]; }
    }
    b2f_multi_kernel<<<dim3(33, 14), 256, 0, stream>>>(mp, flag);

    // --- layer 1: knn(6) + pointnet(h=pos) ---
    knn_kernel<6><<<dim3(N / 256, B), 256, 0, stream>>>(posf, idx1, N);
    pointnet3_kernel<<<dim3(N / 64, B), 64, 0, stream>>>(posf, idx1, W1a, b1a, W1b, b1b, h1, N, 6);

    // --- fps -> 1024, gather ---
    fps_kernel<2048><<<dim3(B), 256, 0, stream>>>(posf, sel1, 1024);
    gather_kernel<<<dim3(1024 * 64 / 256, B), 256, 0, stream>>>(posf, h1, sel1, p2, h2in, N, 1024);

    // --- layer 2: knn(4) + pointnet ---
    knn_kernel<4><<<dim3(1024 / 256, B), 256, 0, stream>>>(p2, idx2, 1024);
    pointnet64_kernel<<<dim3(1024 / 64, B), 64, 0, stream>>>(h2in, p2, idx2, W2a, b2a, W2b, b2b,
                                                             h2out, 1024, 4);

    // --- fps -> 512, gather ---
    fps_kernel<1024><<<dim3(B), 256, 0, stream>>>(p2, sel2, 512);
    gather_kernel<<<dim3(512 * 64 / 256, B), 256, 0, stream>>>(p2, h2out, sel2, p3, h3in, 1024, 512);

    // --- layer 3: knn(3) + pointnet ---
    knn_kernel<3><<<dim3(512 / 256, B), 256, 0, stream>>>(p3, idx3, 512);
    pointnet64_kernel<<<dim3(512 / 64, B), 64, 0, stream>>>(h3in, p3, idx3, W3a, b3a, W3b, b3b,
                                                            h3out, 512, 3);

    // --- head ---
    head_kernel<<<dim3(B), 64, 0, stream>>>(h3out, Wr, br, d_out, 512, flag);
}

// Round 2
// 2275.615 us; speedup vs baseline: 1.3077x; 1.3077x over previous
//
#include <hip/hip_runtime.h>
#include <hip/hip_bf16.h>
#include <math.h>

// Problem constants (from reference): B graphs, N points, C=64 channels.
constexpr int B = 32;
constexpr int N = 2048;

// ---------------------------------------------------------------------------
// dtype sniffer: decides whether float inputs are bf16 (expected) or fp32.
// ---------------------------------------------------------------------------
__global__ void detect_kernel(const unsigned int* __restrict__ raw, int* __restrict__ flag) {
    __shared__ int cnt;
    if (threadIdx.x == 0) cnt = 0;
    __syncthreads();
    int c = 0;
    for (int i = threadIdx.x; i < 4096; i += 256) {
        unsigned h = (raw[i] >> 8) & 0x7f;
        if (h >= 0x3a && h <= 0x41) c++;
    }
    atomicAdd(&cnt, c);
    __syncthreads();
    if (threadIdx.x == 0) *flag = (cnt > (4096 * 55) / 100) ? 1 : 0;
}

__global__ void b2f_kernel(const void* __restrict__ in, float* __restrict__ out, int n,
                           const int* __restrict__ flag) {
    int i = blockIdx.x * 256 + threadIdx.x;
    if (i >= n) return;
    if (*flag) out[i] = __bfloat162float(((const __hip_bfloat16*)in)[i]);
    else       out[i] = ((const float*)in)[i];
}

struct B2FMulti {
    const void* src[14];
    float* dst[14];
    int n[14];
};

__global__ void b2f_multi_kernel(B2FMulti p, const int* __restrict__ flag) {
    int a = blockIdx.y;
    int i = blockIdx.x * 256 + threadIdx.x;
    if (i >= p.n[a]) return;
    if (*flag) p.dst[a][i] = __bfloat162float(((const __hip_bfloat16*)p.src[a])[i]);
    else       p.dst[a][i] = ((const float*)p.src[a])[i];
}

// ---------------------------------------------------------------------------
// KNN (unchanged from round 1 — exact-match semantics, ~20us total).
// ---------------------------------------------------------------------------
template <int K>
__global__ void __launch_bounds__(256) knn_kernel(const float* __restrict__ pos,
                                                  int* __restrict__ idx_out, int n) {
    #pragma clang fp contract(off)
    const int b = blockIdx.y;
    const int i = blockIdx.x * 256 + threadIdx.x;
    const float* pb = pos + (size_t)b * n * 3;
    const float xi = pb[i * 3 + 0], yi = pb[i * 3 + 1], zi = pb[i * 3 + 2];

    float bd[K];
    int   bi_[K];
    #pragma unroll
    for (int q = 0; q < K; ++q) { bd[q] = __builtin_inff(); bi_[q] = 0x7fffffff; }

    __shared__ float tx[256], ty[256], tz[256];
    for (int t0 = 0; t0 < n; t0 += 256) {
        __syncthreads();
        {
            int j = t0 + threadIdx.x;
            tx[threadIdx.x] = pb[j * 3 + 0];
            ty[threadIdx.x] = pb[j * 3 + 1];
            tz[threadIdx.x] = pb[j * 3 + 2];
        }
        __syncthreads();
        for (int jj = 0; jj < 256; ++jj) {
            float dx = xi - tx[jj], dy = yi - ty[jj], dz = zi - tz[jj];
            float d2 = (dx * dx + dy * dy) + dz * dz;
            int jg = t0 + jj;
            if (d2 < bd[K - 1] || (d2 == bd[K - 1] && jg < bi_[K - 1])) {
                bd[K - 1] = d2; bi_[K - 1] = jg;
                #pragma unroll
                for (int q = K - 1; q > 0; --q) {
                    bool sw = (bd[q] < bd[q - 1]) || (bd[q] == bd[q - 1] && bi_[q] < bi_[q - 1]);
                    if (sw) {
                        float td = bd[q]; bd[q] = bd[q - 1]; bd[q - 1] = td;
                        int   ti = bi_[q]; bi_[q] = bi_[q - 1]; bi_[q - 1] = ti;
                    }
                }
            }
        }
    }
    int* op = idx_out + ((size_t)b * n + i) * K;
    #pragma unroll
    for (int q = 0; q < K; ++q) op[q] = bi_[q];
}

// ---------------------------------------------------------------------------
// FPS phase operating entirely in LDS: no global ops in the loop (so the
// per-iteration barrier drains only lgkmcnt), packed u64 (d2,~idx) keys so
// every reduce step is a single compare. Exact semantics preserved:
// max key == (max d2, tie -> lowest idx) == jnp.argmax of the same fp32 d.
// ---------------------------------------------------------------------------
template <int NPTS>
__device__ __forceinline__ void fps_phase(const float* __restrict__ px,
                                          const float* __restrict__ py,
                                          const float* __restrict__ pz,
                                          int* __restrict__ sel_lds,
                                          unsigned long long* __restrict__ slots,
                                          int m, int t) {
    #pragma clang fp contract(off)
    constexpr int P = NPTS / 256;
    float d[P], ox[P], oy[P], oz[P];
    unsigned int nk[P];
    const float sx = px[0], sy = py[0], sz = pz[0];
    #pragma unroll
    for (int p = 0; p < P; ++p) {
        const int ii = t * P + p;
        ox[p] = px[ii]; oy[p] = py[ii]; oz[p] = pz[ii];
        float dx = ox[p] - sx, dy = oy[p] - sy, dz = oz[p] - sz;
        d[p] = (dx * dx + dy * dy) + dz * dz;
        nk[p] = ~(unsigned)ii;
    }
    if (t == 0) sel_lds[0] = 0;

    for (int it = 1; it < m; ++it) {
        // local scan: packed keys, single-compare max
        unsigned long long kb = ((unsigned long long)__float_as_uint(d[0]) << 32) | nk[0];
        #pragma unroll
        for (int p = 1; p < P; ++p) {
            unsigned long long key = ((unsigned long long)__float_as_uint(d[p]) << 32) | nk[p];
            if (key > kb) kb = key;
        }
        // wave butterfly (6 steps, one u64 compare each)
        #pragma unroll
        for (int o = 1; o < 64; o <<= 1) {
            unsigned long long other = __shfl_xor(kb, o, 64);
            if (other > kb) kb = other;
        }
        if ((t & 63) == 0) slots[(it & 1) * 4 + (t >> 6)] = kb;
        __syncthreads();
        {
            const unsigned long long* sp = slots + (it & 1) * 4;
            unsigned long long k0 = sp[0], k1 = sp[1], k2 = sp[2], k3 = sp[3];
            if (k1 > k0) k0 = k1;
            if (k3 > k2) k2 = k3;
            kb = (k2 > k0) ? k2 : k0;
        }
        const int bix = (int)(~(unsigned)(kb & 0xffffffffULL));
        if (t == 0) sel_lds[it] = bix;
        const float nx = px[bix], ny = py[bix], nz = pz[bix];
        #pragma unroll
        for (int p = 0; p < P; ++p) {
            float dx = ox[p] - nx, dy = oy[p] - ny, dz = oz[p] - nz;
            float dd = (dx * dx + dy * dy) + dz * dz;
            d[p] = fminf(d[p], dd);
        }
    }
    __syncthreads();
}

// ---------------------------------------------------------------------------
// MEGA kernel: blocks [0,32) run the chained FPS (2048->1024 select, LDS
// gather, 1024->512 select) and emit sel1, sel2, p2, p3. Blocks [32,288)
// run pointnet layer 1 (4 independent 64-lane groups per 256-thread block).
// The ~100us of pointnet work hides entirely under the FPS critical path.
// ---------------------------------------------------------------------------
__global__ void __launch_bounds__(256) mega_kernel(
        const float* __restrict__ posf, const int* __restrict__ idx1,
        const float* __restrict__ W1, const float* __restrict__ b1,
        const float* __restrict__ W2, const float* __restrict__ b2,
        float* __restrict__ h1, int* __restrict__ sel1, int* __restrict__ sel2,
        float* __restrict__ p2, float* __restrict__ p3) {
    __shared__ __align__(16) char smem[65536];
    const int t = threadIdx.x;

    if (blockIdx.x < B) {
        // ---------------- FPS chain ----------------
        const int b = blockIdx.x;
        float* px = (float*)smem;              // 2048
        float* py = px + 2048;
        float* pz = py + 2048;
        int*   sel1_l = (int*)(pz + 2048);     // 1024
        float* qx = (float*)(sel1_l + 1024);   // 1024
        float* qy = qx + 1024;
        float* qz = qy + 1024;
        int*   sel2_l = (int*)(qz + 1024);     // 512
        unsigned long long* slots = (unsigned long long*)(sel2_l + 512);  // 8

        const float* pb = posf + (size_t)b * N * 3;
        for (int i = t; i < N; i += 256) {
            px[i] = pb[i * 3 + 0]; py[i] = pb[i * 3 + 1]; pz[i] = pb[i * 3 + 2];
        }
        __syncthreads();

        fps_phase<2048>(px, py, pz, sel1_l, slots, 1024, t);

        // compact selected coords into q (LDS->LDS), flush sel1
        for (int i = t; i < 1024; i += 256) {
            int s = sel1_l[i];
            qx[i] = px[s]; qy[i] = py[s]; qz[i] = pz[s];
            sel1[(size_t)b * 1024 + i] = s;
        }
        __syncthreads();
        for (int i = t; i < 1024; i += 256) {
            float* pp = p2 + ((size_t)b * 1024 + i) * 3;
            pp[0] = qx[i]; pp[1] = qy[i]; pp[2] = qz[i];
        }

        fps_phase<1024>(qx, qy, qz, sel2_l, slots, 512, t);

        for (int i = t; i < 512; i += 256) {
            int s = sel2_l[i];
            sel2[(size_t)b * 512 + i] = s;
            float* pp = p3 + ((size_t)b * 512 + i) * 3;
            pp[0] = qx[s]; pp[1] = qy[s]; pp[2] = qz[s];
        }
    } else {
        // ---------------- pointnet layer 1 (CHIN=3, DIN=9, k=6) ----------------
        const int lane = t & 63, g = t >> 6;
        float* al = (float*)smem + g * 4096;   // 64x64 tile per group
        const int flat = (blockIdx.x - B) * 256 + t;
        const int b = flat >> 11;              // N = 2048
        const int i = flat & (N - 1);
        const float* pb = posf + (size_t)b * N * 3;
        const float xi = pb[i * 3 + 0], yi = pb[i * 3 + 1], zi = pb[i * 3 + 2];

        float acc[64];
        #pragma unroll
        for (int c = 0; c < 64; ++c) acc[c] = -__builtin_inff();

        const int* idxp = idx1 + (size_t)flat * 6;
        for (int kk = 0; kk < 6; ++kk) {
            const int j = idxp[kk];
            const float xj = pb[j * 3 + 0], yj = pb[j * 3 + 1], zj = pb[j * 3 + 2];
            const float mv[9] = {xi, yi, zi, xj, yj, zj, xj - xi, yj - yi, zj - zi};
            float a[64];
            #pragma unroll
            for (int e = 0; e < 64; ++e) a[e] = b1[e];
            #pragma unroll
            for (int d = 0; d < 9; ++d) {
                #pragma unroll
                for (int e = 0; e < 64; ++e) a[e] = fmaf(mv[d], W1[d * 64 + e], a[e]);
            }
            __syncthreads();
            #pragma unroll
            for (int e = 0; e < 64; ++e) al[e * 64 + lane] = fmaxf(a[e], 0.f);
            __syncthreads();
            float o[64];
            #pragma unroll
            for (int c = 0; c < 64; ++c) o[c] = b2[c];
            for (int e = 0; e < 64; ++e) {
                float av = al[e * 64 + lane];
                #pragma unroll
                for (int c = 0; c < 64; ++c) o[c] = fmaf(av, W2[e * 64 + c], o[c]);
            }
            #pragma unroll
            for (int c = 0; c < 64; ++c) acc[c] = fmaxf(acc[c], o[c]);
        }
        float* op = h1 + (size_t)flat * 64;
        #pragma unroll
        for (int c = 0; c < 64; ++c) op[c] = fmaxf(acc[c], 0.f);
    }
}

// ---------------------------------------------------------------------------
// Gather h by fps selection (pos gathers now happen inside mega_kernel).
// ---------------------------------------------------------------------------
__global__ void gather_h_kernel(const float* __restrict__ h_in, const int* __restrict__ sel,
                                float* __restrict__ h_out, int n_in, int m) {
    const int b = blockIdx.y;
    const int tid = blockIdx.x * 256 + threadIdx.x;
    const int p = tid >> 6, c = tid & 63;
    if (p >= m) return;
    const int s = sel[(size_t)b * m + p];
    h_out[((size_t)b * m + p) * 64 + c] = h_in[((size_t)b * n_in + s) * 64 + c];
}

// ---------------------------------------------------------------------------
// PointNet layer, CHIN=64 (layers 2/3: DIN = 131) — unchanged from round 1.
// ---------------------------------------------------------------------------
__global__ void __launch_bounds__(64) pointnet64_kernel(
        const float* __restrict__ h_in, const float* __restrict__ pos,
        const int* __restrict__ idx,
        const float* __restrict__ W1, const float* __restrict__ b1,
        const float* __restrict__ W2, const float* __restrict__ b2,
        float* __restrict__ out, int n, int k) {
    const int b = blockIdx.y, lane = threadIdx.x;
    const int i = blockIdx.x * 64 + lane;
    const float* pb = pos + (size_t)b * n * 3;
    const float* hb = h_in + (size_t)b * n * 64;
    const float xi = pb[i * 3 + 0], yi = pb[i * 3 + 1], zi = pb[i * 3 + 2];

    __shared__ float a_lds[64 * 64];

    float acc[64];
    #pragma unroll
    for (int c = 0; c < 64; ++c) acc[c] = -__builtin_inff();

    const int* idxp = idx + ((size_t)b * n + i) * k;
    const float* hi = hb + (size_t)i * 64;
    for (int kk = 0; kk < k; ++kk) {
        const int j = idxp[kk];
        const float xj = pb[j * 3 + 0], yj = pb[j * 3 + 1], zj = pb[j * 3 + 2];
        const float* hj = hb + (size_t)j * 64;

        float a[64];
        #pragma unroll
        for (int e = 0; e < 64; ++e) a[e] = b1[e];

        for (int d4 = 0; d4 < 16; ++d4) {
            float4 v = *(const float4*)(hi + d4 * 4);
            const float mu[4] = {v.x, v.y, v.z, v.w};
            const float* wr = W1 + (size_t)(d4 * 4) * 64;
            #pragma unroll
            for (int u = 0; u < 4; ++u) {
                #pragma unroll
                for (int e = 0; e < 64; ++e) a[e] = fmaf(mu[u], wr[u * 64 + e], a[e]);
            }
        }
        for (int d4 = 0; d4 < 16; ++d4) {
            float4 v = *(const float4*)(hj + d4 * 4);
            const float mu[4] = {v.x, v.y, v.z, v.w};
            const float* wr = W1 + (size_t)(64 + d4 * 4) * 64;
            #pragma unroll
            for (int u = 0; u < 4; ++u) {
                #pragma unroll
                for (int e = 0; e < 64; ++e) a[e] = fmaf(mu[u], wr[u * 64 + e], a[e]);
            }
        }
        {
            const float mr[3] = {xj - xi, yj - yi, zj - zi};
            #pragma unroll
            for (int d = 0; d < 3; ++d) {
                #pragma unroll
                for (int e = 0; e < 64; ++e) a[e] = fmaf(mr[d], W1[(128 + d) * 64 + e], a[e]);
            }
        }
        __syncthreads();
        #pragma unroll
        for (int e = 0; e < 64; ++e) a_lds[e * 64 + lane] = fmaxf(a[e], 0.f);
        __syncthreads();
        float o[64];
        #pragma unroll
        for (int c = 0; c < 64; ++c) o[c] = b2[c];
        for (int e = 0; e < 64; ++e) {
            float av = a_lds[e * 64 + lane];
            #pragma unroll
            for (int c = 0; c < 64; ++c) o[c] = fmaf(av, W2[e * 64 + c], o[c]);
        }
        #pragma unroll
        for (int c = 0; c < 64; ++c) acc[c] = fmaxf(acc[c], o[c]);
    }
    float* op = out + ((size_t)b * n + i) * 64;
    #pragma unroll
    for (int c = 0; c < 64; ++c) op[c] = fmaxf(acc[c], 0.f);
}

// ---------------------------------------------------------------------------
// Head: global max over points then [64]x[64,6] linear. One block per graph.
// ---------------------------------------------------------------------------
__global__ void __launch_bounds__(64) head_kernel(const float* __restrict__ h,
                                                  const float* __restrict__ Wr,
                                                  const float* __restrict__ br,
                                                  void* __restrict__ out, int n,
                                                  const int* __restrict__ flag) {
    const int b = blockIdx.x, lane = threadIdx.x;
    const float* hb = h + (size_t)b * n * 64;
    float g = -__builtin_inff();
    for (int i = 0; i < n; ++i) g = fmaxf(g, hb[(size_t)i * 64 + lane]);
    __shared__ float gl[64];
    gl[lane] = g;
    __syncthreads();
    if (lane < 6) {
        float o = br[lane];
        #pragma unroll
        for (int c = 0; c < 64; ++c) o = fmaf(gl[c], Wr[c * 6 + lane], o);
        if (*flag) ((__hip_bfloat16*)out)[b * 6 + lane] = __float2bfloat16(o);
        else       ((float*)out)[b * 6 + lane] = o;
    }
}

// ---------------------------------------------------------------------------
extern "C" void kernel_launch(void* const* d_in, const int* in_sizes, int n_in,
                              void* d_out, int out_size, void* d_ws, size_t ws_size,
                              hipStream_t stream) {
    (void)in_sizes; (void)n_in; (void)out_size; (void)ws_size;

    char* w = (char*)d_ws;
    auto alloc = [&](size_t nbytes) -> void* {
        void* p = (void*)w;
        w += (nbytes + 255) & ~(size_t)255;
        return p;
    };

    int*   flag = (int*)alloc(4);
    float* posf = (float*)alloc((size_t)B * N * 3 * 4);
    float* W1a = (float*)alloc(9 * 64 * 4);    float* b1a = (float*)alloc(64 * 4);
    float* W1b = (float*)alloc(64 * 64 * 4);   float* b1b = (float*)alloc(64 * 4);
    float* W2a = (float*)alloc(131 * 64 * 4);  float* b2a = (float*)alloc(64 * 4);
    float* W2b = (float*)alloc(64 * 64 * 4);   float* b2b = (float*)alloc(64 * 4);
    float* W3a = (float*)alloc(131 * 64 * 4);  float* b3a = (float*)alloc(64 * 4);
    float* W3b = (float*)alloc(64 * 64 * 4);   float* b3b = (float*)alloc(64 * 4);
    float* Wr  = (float*)alloc(64 * 6 * 4);    float* br  = (float*)alloc(6 * 4);

    float* h1    = (float*)alloc((size_t)B * N * 64 * 4);       // 16 MB (re-sliced below)
    int*   idx1  = (int*)alloc((size_t)B * N * 6 * 4);
    int*   sel1  = (int*)alloc((size_t)B * 1024 * 4);
    float* p2    = (float*)alloc((size_t)B * 1024 * 3 * 4);
    float* h2in  = (float*)alloc((size_t)B * 1024 * 64 * 4);
    int*   idx2  = (int*)alloc((size_t)B * 1024 * 4 * 4);
    int*   sel2  = (int*)alloc((size_t)B * 512 * 4);
    float* p3    = (float*)alloc((size_t)B * 512 * 3 * 4);
    int*   idx3  = (int*)alloc((size_t)B * 512 * 3 * 4);
    // Alias later stages into h1's 16 MB once h1 is consumed (after gather_h1):
    float* h2out = h1;                                           // 8 MB
    float* h3in  = h1 + (size_t)B * 1024 * 64;                   // 4 MB
    float* h3out = h1 + (size_t)B * 1024 * 64 + (size_t)B * 512 * 64; // 4 MB

    // --- dtype detect + convert everything to fp32 in ws ---
    detect_kernel<<<dim3(1), 256, 0, stream>>>((const unsigned int*)d_in[1], flag);
    b2f_kernel<<<dim3((B * N * 3 + 255) / 256), 256, 0, stream>>>(d_in[1], posf, B * N * 3, flag);
    B2FMulti mp;
    {
        const int   wi[14] = {3, 4, 5, 6, 7, 8, 9, 10, 11, 12, 13, 14, 15, 16};
        float*      wd[14] = {W1a, b1a, W1b, b1b, W2a, b2a, W2b, b2b, W3a, b3a, W3b, b3b, Wr, br};
        const int   wn[14] = {576, 64, 4096, 64, 8384, 64, 4096, 64, 8384, 64, 4096, 64, 384, 6};
        for (int q = 0; q < 14; ++q) { mp.src[q] = d_in[wi[q]]; mp.dst[q] = wd[q]; mp.n[q] = wn[q]; }
    }
    b2f_multi_kernel<<<dim3(33, 14), 256, 0, stream>>>(mp, flag);

    // --- knn1 (needed by the fused pointnet-1 blocks in mega) ---
    knn_kernel<6><<<dim3(N / 256, B), 256, 0, stream>>>(posf, idx1, N);

    // --- MEGA: fps chain (32 blocks) + pointnet layer 1 (256 blocks) ---
    mega_kernel<<<dim3(B + (B * N) / 256), 256, 0, stream>>>(posf, idx1, W1a, b1a, W1b, b1b,
                                                             h1, sel1, sel2, p2, p3);

    // --- gather h for layer 2, knn2, pointnet layer 2 ---
    gather_h_kernel<<<dim3(1024 * 64 / 256, B), 256, 0, stream>>>(h1, sel1, h2in, N, 1024);
    knn_kernel<4><<<dim3(1024 / 256, B), 256, 0, stream>>>(p2, idx2, 1024);
    pointnet64_kernel<<<dim3(1024 / 64, B), 64, 0, stream>>>(h2in, p2, idx2, W2a, b2a, W2b, b2b,
                                                             h2out, 1024, 4);

    // --- gather h for layer 3, knn3, pointnet layer 3 ---
    gather_h_kernel<<<dim3(512 * 64 / 256, B), 256, 0, stream>>>(h2out, sel2, h3in, 1024, 512);
    knn_kernel<3><<<dim3(512 / 256, B), 256, 0, stream>>>(p3, idx3, 512);
    pointnet64_kernel<<<dim3(512 / 64, B), 64, 0, stream>>>(h3in, p3, idx3, W3a, b3a, W3b, b3b,
                                                            h3out, 512, 3);

    // --- head ---
    head_kernel<<<dim3(B), 64, 0, stream>>>(h3out, Wr, br, d_out, 512, flag);
}